// Round 1
// baseline (1571.418 us; speedup 1.0000x reference)
//
#include <hip/hip_runtime.h>
#include <math.h>

// Problem constants (fixed by the reference)
constexpr int QLEN_C  = 1024;
constexpr int BSZ_C   = 4;
constexpr int DMODEL  = 1024;
constexpr int NHEAD_C = 16;
constexpr int DHEAD_C = 64;
constexpr float SCALE = 0.125f;   // 1/sqrt(64)
constexpr float NEGF  = -1e30f;

// ---------------------------------------------------------------------------
// Generic fp32 GEMM: C[M,N] = A[M,K] @ B[K,N], all row-major, M%64==0, N%64==0,
// K%16==0. 256 threads, 64x64 tile, BK=16, 4x4 register blocking.
// ---------------------------------------------------------------------------
__global__ __launch_bounds__(256)
void gemm_kernel(const float* __restrict__ A, const float* __restrict__ B,
                 float* __restrict__ C, int M, int N, int K)
{
    constexpr int BM = 64, BN = 64, BK = 16, LP = 68; // LP: pad keeps 16B align, 2-way banks
    __shared__ float As[BK][LP];
    __shared__ float Bs[BK][LP];

    const int tid = threadIdx.x;
    const int tx = tid & 15, ty = tid >> 4;
    const int row0 = blockIdx.y * BM, col0 = blockIdx.x * BN;

    float acc[4][4] = {};

    for (int k0 = 0; k0 < K; k0 += BK) {
        #pragma unroll
        for (int e = 0; e < (BM * BK) / 256; ++e) {       // A tile 64x16
            int idx = tid + e * 256;
            int m = idx >> 4, kk = idx & 15;
            As[kk][m] = A[(row0 + m) * K + k0 + kk];
        }
        #pragma unroll
        for (int e = 0; e < (BK * BN) / 256; ++e) {       // B tile 16x64
            int idx = tid + e * 256;
            int kk = idx >> 6, nn = idx & 63;
            Bs[kk][nn] = B[(k0 + kk) * N + col0 + nn];
        }
        __syncthreads();
        #pragma unroll
        for (int kk = 0; kk < BK; ++kk) {
            float4 a4 = *(const float4*)&As[kk][ty * 4];
            float4 b4 = *(const float4*)&Bs[kk][tx * 4];
            float a[4] = {a4.x, a4.y, a4.z, a4.w};
            float b[4] = {b4.x, b4.y, b4.z, b4.w};
            #pragma unroll
            for (int i = 0; i < 4; ++i)
                #pragma unroll
                for (int j = 0; j < 4; ++j)
                    acc[i][j] += a[i] * b[j];
        }
        __syncthreads();
    }
    #pragma unroll
    for (int i = 0; i < 4; ++i) {
        float4 cv = make_float4(acc[i][0], acc[i][1], acc[i][2], acc[i][3]);
        *(float4*)&C[(row0 + ty * 4 + i) * N + col0 + tx * 4] = cv;
    }
}

// ---------------------------------------------------------------------------
// c[n][jr] = sum_d (rrb[n,d]-rwb[n,d]) * rk[jr, n*64+d]
// (the i-independent part of the BD term)
// ---------------------------------------------------------------------------
__global__ __launch_bounds__(256)
void cbias_kernel(const float* __restrict__ rk, const float* __restrict__ rwb,
                  const float* __restrict__ rrb, float* __restrict__ cbuf)
{
    int idx = blockIdx.x * 256 + threadIdx.x;      // n*1024 + jr, 16384 total
    int n = idx >> 10, jr = idx & 1023;
    float s = 0.f;
    #pragma unroll 8
    for (int d = 0; d < DHEAD_C; ++d)
        s += (rrb[n * 64 + d] - rwb[n * 64 + d]) * rk[jr * DMODEL + n * 64 + d];
    cbuf[idx] = s;
}

// ---------------------------------------------------------------------------
// Flash-style attention with fused rel-shift.
// One block per (b, n, i-tile of 32). 256 threads.
//   S[i][j] = SCALE * ( qa_i . k_j  +  qa_i . rk[QLEN-1-(i-j)]  + c[n, jr] )
// where qa = q + r_w_bias, c[n,jr] = (rrb-rwb).rk[jr].  j>i masked.
// Online softmax; per-row m/l kept redundantly in the 16 owning lanes.
// ---------------------------------------------------------------------------
constexpr int IT = 32, JT = 32, RT = 64, PADL = 65;

__global__ __launch_bounds__(256)
void attn_kernel(const float* __restrict__ heads, const float* __restrict__ rk,
                 const float* __restrict__ cbuf, const float* __restrict__ rwb,
                 float* __restrict__ vec)
{
    __shared__ float qa[IT][PADL];
    __shared__ float kt[JT][PADL];
    __shared__ float vt[JT][PADL];
    __shared__ float rkt[RT][PADL];
    __shared__ float sp[IT][JT + 1];
    __shared__ float c_l[RT];

    const int tid = threadIdx.x;
    const int ti = blockIdx.x;
    const int bn = blockIdx.y;
    const int b = bn & 3, n = bn >> 2;
    const int i0 = ti * IT;

    const int ty = tid >> 4, tx = tid & 15;
    const int ii0s = ty * 2;          // two S rows per thread
    const int jj0s = tx * 2;          // two S cols per thread
    const int d0p = tx * 4;           // PV: 4 d-columns per thread (rows = ii0s,+1)

    // stage Q tile (+ r_w_bias)
    #pragma unroll
    for (int e = 0; e < (IT * DHEAD_C) / 256; ++e) {
        int idx = tid + e * 256;
        int row = idx >> 6, d = idx & 63;
        qa[row][d] = heads[((i0 + row) * BSZ_C + b) * (3 * DMODEL) + n * 64 + d]
                     + rwb[n * 64 + d];
    }

    float o[2][4] = {};
    float m_r[2] = {-3.0e38f, -3.0e38f};
    float l_r[2] = {0.f, 0.f};

    for (int j0 = 0; j0 <= i0 + IT - 1; j0 += JT) {
        __syncthreads();   // previous PV reads done before overwrite
        // stage K/V tiles
        #pragma unroll
        for (int e = 0; e < (JT * DHEAD_C) / 256; ++e) {
            int idx = tid + e * 256;
            int row = idx >> 6, d = idx & 63;
            int base = ((j0 + row) * BSZ_C + b) * (3 * DMODEL) + n * 64 + d;
            kt[row][d] = heads[base + DMODEL];
            vt[row][d] = heads[base + 2 * DMODEL];
        }
        // stage rk rows: t = (IT-1-ii)+jj -> jr = jrbase + t
        const int jrbase = QLEN_C - IT - i0 + j0;
        #pragma unroll
        for (int e = 0; e < (RT * DHEAD_C) / 256; ++e) {
            int idx = tid + e * 256;
            int row = idx >> 6, d = idx & 63;
            int jr = jrbase + row;
            rkt[row][d] = (jr >= 0 && jr < QLEN_C) ? rk[jr * DMODEL + n * 64 + d] : 0.f;
        }
        if (tid < RT) {
            int jr = jrbase + tid;
            c_l[tid] = (jr >= 0 && jr < QLEN_C) ? cbuf[n * QLEN_C + jr] : 0.f;
        }
        __syncthreads();

        // ---- S phase: 2x2 scores per thread ----
        float accA[2][2] = {}, accB[2][2] = {};
        const int tb = (IT - 1) - (ii0s + 1) + jj0s;   // min t for this thread
        #pragma unroll 4
        for (int d = 0; d < DHEAD_C; ++d) {
            float a0 = qa[ii0s][d],     a1 = qa[ii0s + 1][d];
            float k0 = kt[jj0s][d],     k1 = kt[jj0s + 1][d];
            float r0 = rkt[tb][d], r1 = rkt[tb + 1][d], r2 = rkt[tb + 2][d];
            accA[0][0] += a0 * k0;  accA[0][1] += a0 * k1;
            accA[1][0] += a1 * k0;  accA[1][1] += a1 * k1;
            accB[0][0] += a0 * r1;  accB[0][1] += a0 * r2;   // u = 1-i2+j2
            accB[1][0] += a1 * r0;  accB[1][1] += a1 * r1;
        }

        float alpha[2];
        #pragma unroll
        for (int i2 = 0; i2 < 2; ++i2) {
            const int gi = i0 + ii0s + i2;
            float s[2];
            float mx = -3.0e38f;
            #pragma unroll
            for (int j2 = 0; j2 < 2; ++j2) {
                int gj = j0 + jj0s + j2;
                int t = tb + 1 - i2 + j2;
                float v = SCALE * (accA[i2][j2] + accB[i2][j2] + c_l[t]);
                s[j2] = (gj <= gi) ? v : NEGF;
                mx = fmaxf(mx, s[j2]);
            }
            // reduce across the 16 lanes owning this row (lanes share ty)
            #pragma unroll
            for (int msk = 1; msk < 16; msk <<= 1)
                mx = fmaxf(mx, __shfl_xor(mx, msk, 64));
            float mnew = fmaxf(m_r[i2], mx);
            alpha[i2] = __expf(m_r[i2] - mnew);
            float ps = 0.f;
            #pragma unroll
            for (int j2 = 0; j2 < 2; ++j2) {
                float p = __expf(s[j2] - mnew);
                sp[ii0s + i2][jj0s + j2] = p;
                ps += p;
            }
            #pragma unroll
            for (int msk = 1; msk < 16; msk <<= 1)
                ps += __shfl_xor(ps, msk, 64);
            l_r[i2] = l_r[i2] * alpha[i2] + ps;
            m_r[i2] = mnew;
        }
        __syncthreads();

        // ---- PV phase: O[2 rows][4 d] += P @ V ----
        #pragma unroll
        for (int e = 0; e < 4; ++e) { o[0][e] *= alpha[0]; o[1][e] *= alpha[1]; }
        const int jcnt = min(JT, i0 + IT - j0);   // cols beyond i0+IT-1 have p==0
        for (int jj = 0; jj < jcnt; ++jj) {
            float p0 = sp[ii0s][jj], p1 = sp[ii0s + 1][jj];
            #pragma unroll
            for (int e = 0; e < 4; ++e) {
                float vv = vt[jj][d0p + e];
                o[0][e] += p0 * vv;
                o[1][e] += p1 * vv;
            }
        }
    }

    // normalize and store vec[i, b, n*64+d]
    #pragma unroll
    for (int i2 = 0; i2 < 2; ++i2) {
        float rinv = 1.f / l_r[i2];
        float4 ov = make_float4(o[i2][0] * rinv, o[i2][1] * rinv,
                                o[i2][2] * rinv, o[i2][3] * rinv);
        int row = i0 + ii0s + i2;
        *(float4*)&vec[(row * BSZ_C + b) * DMODEL + n * 64 + d0p] = ov;
    }
}

// ---------------------------------------------------------------------------
// out = LayerNorm(w + attn_out) * gamma + beta  — one block per row
// ---------------------------------------------------------------------------
__global__ __launch_bounds__(256)
void ln_kernel(const float* __restrict__ w, const float* __restrict__ attn,
               const float* __restrict__ gamma, const float* __restrict__ beta,
               float* __restrict__ out)
{
    const int row = blockIdx.x;
    const int tid = threadIdx.x;
    const float* xw = w + row * DMODEL;
    const float* xa = attn + row * DMODEL;

    float x[4];
    float s = 0.f;
    #pragma unroll
    for (int e = 0; e < 4; ++e) {
        int c = tid + e * 256;
        x[e] = xw[c] + xa[c];
        s += x[e];
    }
    __shared__ float red[6];
    #pragma unroll
    for (int m = 1; m < 64; m <<= 1) s += __shfl_xor(s, m, 64);
    int wv = tid >> 6, ln = tid & 63;
    if (ln == 0) red[wv] = s;
    __syncthreads();
    if (tid == 0) red[4] = red[0] + red[1] + red[2] + red[3];
    __syncthreads();
    float mu = red[4] * (1.f / DMODEL);

    float vs = 0.f;
    #pragma unroll
    for (int e = 0; e < 4; ++e) { float d = x[e] - mu; vs += d * d; }
    #pragma unroll
    for (int m = 1; m < 64; m <<= 1) vs += __shfl_xor(vs, m, 64);
    if (ln == 0) red[wv] = vs;
    __syncthreads();
    if (tid == 0) red[5] = red[0] + red[1] + red[2] + red[3];
    __syncthreads();
    float var = red[5] * (1.f / DMODEL);
    float inv = rsqrtf(var + 1e-5f);

    #pragma unroll
    for (int e = 0; e < 4; ++e) {
        int c = tid + e * 256;
        out[row * DMODEL + c] = (x[e] - mu) * inv * gamma[c] + beta[c];
    }
}

// ---------------------------------------------------------------------------
extern "C" void kernel_launch(void* const* d_in, const int* in_sizes, int n_in,
                              void* d_out, int out_size, void* d_ws, size_t ws_size,
                              hipStream_t stream)
{
    const float* w     = (const float*)d_in[0];
    const float* r     = (const float*)d_in[1];
    const float* rwb   = (const float*)d_in[2];
    const float* rrb   = (const float*)d_in[3];
    // d_in[4] = attn_mask: deterministically causal-tril, applied analytically.
    const float* Wqkv  = (const float*)d_in[5];
    const float* Wr    = (const float*)d_in[6];
    const float* Wo    = (const float*)d_in[7];
    const float* gamma = (const float*)d_in[8];
    const float* beta  = (const float*)d_in[9];
    float* out = (float*)d_out;

    float* ws     = (float*)d_ws;
    float* heads  = ws;                         // 4096 x 3072
    float* rkbuf  = heads + 4096 * 3072;        // 1024 x 1024
    float* cbuf   = rkbuf + 1024 * 1024;        // 16 x 1024
    float* vec    = cbuf + 16 * 1024;           // 4096 x 1024
    float* attno  = vec + 4096 * 1024;          // 4096 x 1024

    // 1) heads = w @ W_qkv   [4096,1024]x[1024,3072]
    gemm_kernel<<<dim3(3072 / 64, 4096 / 64), 256, 0, stream>>>(w, Wqkv, heads, 4096, 3072, 1024);
    // 2) r_k = r @ W_r       [1024,1024]x[1024,1024]
    gemm_kernel<<<dim3(1024 / 64, 1024 / 64), 256, 0, stream>>>(r, Wr, rkbuf, 1024, 1024, 1024);
    // 3) c[n,jr] = (rrb-rwb).r_k[jr,n,:]
    cbias_kernel<<<64, 256, 0, stream>>>(rkbuf, rwb, rrb, cbuf);
    // 4) flash attention with fused rel-shift -> vec
    attn_kernel<<<dim3(QLEN_C / IT, BSZ_C * NHEAD_C), 256, 0, stream>>>(heads, rkbuf, cbuf, rwb, vec);
    // 5) attn_out = vec @ W_o
    gemm_kernel<<<dim3(1024 / 64, 4096 / 64), 256, 0, stream>>>(vec, Wo, attno, 4096, 1024, 1024);
    // 6) out = LN(w + attn_out)
    ln_kernel<<<4096, 256, 0, stream>>>(w, attno, gamma, beta, out);
}

// Round 3
// 875.679 us; speedup vs baseline: 1.7945x; 1.7945x over previous
//
#include <hip/hip_runtime.h>
#include <math.h>

constexpr int QLEN_C  = 1024;
constexpr int BSZ_C   = 4;
constexpr int DMODEL  = 1024;
constexpr float SCALE = 0.125f;   // 1/sqrt(64)
constexpr float NEGF  = -1e30f;

typedef __attribute__((ext_vector_type(8))) short bh8;   // 8 bf16 (4 VGPRs)
typedef __attribute__((ext_vector_type(4))) float f32x4; // MFMA acc

__device__ inline short f2bf(float f) {
    union { float f; unsigned u; } v; v.f = f;
    unsigned r = v.u + 0x7FFFu + ((v.u >> 16) & 1u);   // round-to-nearest-even
    return (short)(r >> 16);
}

// ---------------------------------------------------------------------------
// fp32 GEMM (verified round 1): C[M,N] = A[M,K] @ B[K,N]
// ---------------------------------------------------------------------------
__global__ __launch_bounds__(256)
void gemm_kernel(const float* __restrict__ A, const float* __restrict__ B,
                 float* __restrict__ C, int M, int N, int K)
{
    constexpr int BM = 64, BN = 64, BK = 16, LP = 68;
    __shared__ float As[BK][LP];
    __shared__ float Bs[BK][LP];

    const int tid = threadIdx.x;
    const int tx = tid & 15, ty = tid >> 4;
    const int row0 = blockIdx.y * BM, col0 = blockIdx.x * BN;

    float acc[4][4] = {};

    for (int k0 = 0; k0 < K; k0 += BK) {
        #pragma unroll
        for (int e = 0; e < (BM * BK) / 256; ++e) {
            int idx = tid + e * 256;
            int m = idx >> 4, kk = idx & 15;
            As[kk][m] = A[(row0 + m) * K + k0 + kk];
        }
        #pragma unroll
        for (int e = 0; e < (BK * BN) / 256; ++e) {
            int idx = tid + e * 256;
            int kk = idx >> 6, nn = idx & 63;
            Bs[kk][nn] = B[(k0 + kk) * N + col0 + nn];
        }
        __syncthreads();
        #pragma unroll
        for (int kk = 0; kk < BK; ++kk) {
            float4 a4 = *(const float4*)&As[kk][ty * 4];
            float4 b4 = *(const float4*)&Bs[kk][tx * 4];
            float a[4] = {a4.x, a4.y, a4.z, a4.w};
            float b[4] = {b4.x, b4.y, b4.z, b4.w};
            #pragma unroll
            for (int i = 0; i < 4; ++i)
                #pragma unroll
                for (int j = 0; j < 4; ++j)
                    acc[i][j] += a[i] * b[j];
        }
        __syncthreads();
    }
    #pragma unroll
    for (int i = 0; i < 4; ++i) {
        float4 cv = make_float4(acc[i][0], acc[i][1], acc[i][2], acc[i][3]);
        *(float4*)&C[(row0 + ty * 4 + i) * N + col0 + tx * 4] = cv;
    }
}

// ---------------------------------------------------------------------------
// prep_rk: rkbuf fp32 [1024][1024] -> rkb bf16 [1088][1024]; rows >=1024 zero
// ---------------------------------------------------------------------------
__global__ __launch_bounds__(256)
void prep_rk(const float* __restrict__ rkbuf, short* __restrict__ rkb)
{
    int idx = (blockIdx.x * 256 + threadIdx.x) * 8;
    int row = idx >> 10;
    bh8 o;
    if (row < 1024) {
        #pragma unroll
        for (int e = 0; e < 8; ++e) o[e] = f2bf(rkbuf[idx + e]);
    } else {
        #pragma unroll
        for (int e = 0; e < 8; ++e) o[e] = 0;
    }
    *(bh8*)(rkb + idx) = o;
}

// ---------------------------------------------------------------------------
// prep_kv: heads fp32 -> kb bf16 [bn][j][64]  and vT bf16 [bn][64][j]
// ---------------------------------------------------------------------------
__global__ __launch_bounds__(256)
void prep_kv(const float* __restrict__ heads, short* __restrict__ kb,
             short* __restrict__ vT)
{
    __shared__ float vtile[64][65];
    const int bn = blockIdx.x, jt = blockIdx.y;
    const int b = bn & 3, n = bn >> 2;
    const int j0 = jt * 64;
    const int t = threadIdx.x;
    const int row = t >> 2, d0 = (t & 3) * 16;

    const float* kp = heads + ((size_t)(j0 + row) * 4 + b) * 3072 + 1024 + n * 64 + d0;
    const float* vp = kp + 1024;

    bh8 k0, k1;
    #pragma unroll
    for (int e = 0; e < 8; ++e) {
        k0[e] = f2bf(kp[e]);
        k1[e] = f2bf(kp[e + 8]);
        vtile[row][d0 + e] = vp[e];
        vtile[row][d0 + e + 8] = vp[e + 8];
    }
    short* kdst = kb + ((size_t)bn * 1024 + j0 + row) * 64 + d0;
    *(bh8*)kdst = k0;
    *(bh8*)(kdst + 8) = k1;

    __syncthreads();

    const int d = t >> 2, jl0 = (t & 3) * 16;
    bh8 v0, v1;
    #pragma unroll
    for (int e = 0; e < 8; ++e) {
        v0[e] = f2bf(vtile[jl0 + e][d]);
        v1[e] = f2bf(vtile[jl0 + e + 8][d]);
    }
    short* vdst = vT + ((size_t)bn * 64 + d) * 1024 + j0 + jl0;
    *(bh8*)vdst = v0;
    *(bh8*)(vdst + 8) = v1;
}

// ---------------------------------------------------------------------------
// MFMA flash attention with fused rel-shift. Grid (16 i-tiles, 64 bn), 256 thr.
// Wave w owns Q rows [i0+16w, i0+16w+16). LDS regions are per-wave, but phase
// boundaries are now __syncthreads()-protected (m120-verified pattern): the
// round-2 barrier-free version relied on within-wave cross-lane DS ordering,
// which is the prime suspect for its 0.416 absmax failure.
// ---------------------------------------------------------------------------
__global__ __launch_bounds__(256)
void attn_mfma(const float* __restrict__ heads, const short* __restrict__ rkb,
               const short* __restrict__ kb, const short* __restrict__ vT,
               const float* __restrict__ rwb, const float* __restrict__ rrb,
               float* __restrict__ vec)
{
    __shared__ alignas(16) float sBt[4][16 * 97];
    __shared__ alignas(16) short sP[4][16 * 80];

    const int tid = threadIdx.x;
    const int wave = tid >> 6, lane = tid & 63;
    const int quad = lane >> 4, c = lane & 15;
    const int i0 = blockIdx.x * 64;
    const int bn = blockIdx.y;
    const int b = bn & 3, n = bn >> 2;
    const int rowsbase = i0 + wave * 16;

    // Q fragments with both biases (A-layout: m=c, k=quad*8+e+32*ks)
    bh8 aAC[2], aBD[2];
    const int dq = n * 64 + quad * 8;
    #pragma unroll
    for (int ks = 0; ks < 2; ++ks) {
        const float* qp = heads + ((size_t)(rowsbase + c) * 4 + b) * 3072 + dq + 32 * ks;
        #pragma unroll
        for (int e = 0; e < 8; ++e) {
            float qv = qp[e];
            aAC[ks][e] = f2bf(qv + rwb[dq + 32 * ks + e]);
            aBD[ks][e] = f2bf(qv + rrb[dq + 32 * ks + e]);
        }
    }

    f32x4 oacc[4];
    #pragma unroll
    for (int dt = 0; dt < 4; ++dt) oacc[dt] = (f32x4)0.0f;
    float m_r[4] = {-3.0e38f, -3.0e38f, -3.0e38f, -3.0e38f};
    float l_r[4] = {0.f, 0.f, 0.f, 0.f};

    float* BtL = &sBt[wave][0];
    short* PL  = &sP[wave][0];
    const short* kbp = kb + (size_t)bn * 1024 * 64;
    const short* vtp = vT + (size_t)bn * 64 * 1024;

    // trip count depends only on i0 (block-uniform) -> barriers are legal
    for (int j0 = 0; j0 <= i0 + 63; j0 += 64) {
        // ---- Bt = (q+rrb) . rk-window (5 column tiles of 16) ----
        const int jrw0 = 1008 - rowsbase + j0;
        f32x4 bt[5];
        #pragma unroll
        for (int tt = 0; tt < 5; ++tt) {
            bt[tt] = (f32x4)0.0f;
            const short* rp = rkb + (size_t)(jrw0 + c + 16 * tt) * 1024 + n * 64 + quad * 8;
            #pragma unroll
            for (int ks = 0; ks < 2; ++ks) {
                bh8 bf = *(const bh8*)(rp + 32 * ks);
                bt[tt] = __builtin_amdgcn_mfma_f32_16x16x32_bf16(aBD[ks], bf, bt[tt], 0, 0, 0);
            }
        }
        // sheared write: value Bt[row][t] -> slot row*97 + row + t
        #pragma unroll
        for (int tt = 0; tt < 5; ++tt)
            #pragma unroll
            for (int r = 0; r < 4; ++r) {
                int row = quad * 4 + r;
                BtL[row * 97 + row + c + 16 * tt] = bt[tt][r];
            }

        // ---- AC = (q+rwb) . K^T (overlaps the Bt LDS drain) ----
        f32x4 ac[4];
        #pragma unroll
        for (int jt = 0; jt < 4; ++jt) {
            ac[jt] = (f32x4)0.0f;
            const short* kp = kbp + (size_t)(j0 + c + 16 * jt) * 64 + quad * 8;
            #pragma unroll
            for (int ks = 0; ks < 2; ++ks) {
                bh8 bf = *(const bh8*)(kp + 32 * ks);
                ac[jt] = __builtin_amdgcn_mfma_f32_16x16x32_bf16(aAC[ks], bf, ac[jt], 0, 0, 0);
            }
        }

        __syncthreads();   // Bt writes visible to all lanes before gather

        // ---- gather + mask + online softmax (row = quad*4+r) ----
        float al[4];
        #pragma unroll
        for (int r = 0; r < 4; ++r) {
            const int row = quad * 4 + r;
            const int gi = rowsbase + row;
            float s[4];
            float mx = -3.0e38f;
            #pragma unroll
            for (int jt = 0; jt < 4; ++jt) {
                int gj = j0 + c + 16 * jt;
                float v = SCALE * (ac[jt][r] + BtL[row * 97 + c + 16 * jt + 15]);
                if (gj > gi) v = NEGF;
                s[jt] = v;
                mx = fmaxf(mx, v);
            }
            #pragma unroll
            for (int msk = 1; msk < 16; msk <<= 1)
                mx = fmaxf(mx, __shfl_xor(mx, msk, 64));
            float mnew = fmaxf(m_r[r], mx);
            al[r] = __expf(m_r[r] - mnew);
            m_r[r] = mnew;
            float ps = 0.f;
            #pragma unroll
            for (int jt = 0; jt < 4; ++jt) {
                float p = __expf(s[jt] - mnew);
                PL[row * 80 + c + 16 * jt] = f2bf(p);
                ps += p;
            }
            #pragma unroll
            for (int msk = 1; msk < 16; msk <<= 1)
                ps += __shfl_xor(ps, msk, 64);
            l_r[r] = l_r[r] * al[r] + ps;
            #pragma unroll
            for (int dt = 0; dt < 4; ++dt) oacc[dt][r] *= al[r];
        }

        __syncthreads();   // P writes visible to all lanes before A-frag reads

        // ---- PV: O += P @ V  (A = P from LDS, B = vT rows, contiguous) ----
        bh8 aP[2];
        #pragma unroll
        for (int ks = 0; ks < 2; ++ks)
            aP[ks] = *(const bh8*)(PL + c * 80 + 32 * ks + quad * 8);
        #pragma unroll
        for (int dt = 0; dt < 4; ++dt) {
            const short* vp = vtp + (size_t)(c + 16 * dt) * 1024 + j0 + quad * 8;
            #pragma unroll
            for (int ks = 0; ks < 2; ++ks) {
                bh8 bf = *(const bh8*)(vp + 32 * ks);
                oacc[dt] = __builtin_amdgcn_mfma_f32_16x16x32_bf16(aP[ks], bf, oacc[dt], 0, 0, 0);
            }
        }
    }

    // epilogue: normalize, store vec[i][b][n*64+d] fp32
    #pragma unroll
    for (int r = 0; r < 4; ++r) {
        float rinv = 1.f / l_r[r];
        int gi = rowsbase + quad * 4 + r;
        float* op = vec + ((size_t)gi * 4 + b) * 1024 + n * 64;
        #pragma unroll
        for (int dt = 0; dt < 4; ++dt)
            op[c + 16 * dt] = oacc[dt][r] * rinv;
    }
}

// ---------------------------------------------------------------------------
// out = LayerNorm(w + attn_out) — one block per row (verified round 1)
// ---------------------------------------------------------------------------
__global__ __launch_bounds__(256)
void ln_kernel(const float* __restrict__ w, const float* __restrict__ attn,
               const float* __restrict__ gamma, const float* __restrict__ beta,
               float* __restrict__ out)
{
    const int row = blockIdx.x;
    const int tid = threadIdx.x;
    const float* xw = w + row * DMODEL;
    const float* xa = attn + row * DMODEL;

    float x[4];
    float s = 0.f;
    #pragma unroll
    for (int e = 0; e < 4; ++e) {
        int cc = tid + e * 256;
        x[e] = xw[cc] + xa[cc];
        s += x[e];
    }
    __shared__ float red[6];
    #pragma unroll
    for (int m = 1; m < 64; m <<= 1) s += __shfl_xor(s, m, 64);
    int wv = tid >> 6, lnid = tid & 63;
    if (lnid == 0) red[wv] = s;
    __syncthreads();
    if (tid == 0) red[4] = red[0] + red[1] + red[2] + red[3];
    __syncthreads();
    float mu = red[4] * (1.f / DMODEL);

    float vs = 0.f;
    #pragma unroll
    for (int e = 0; e < 4; ++e) { float d = x[e] - mu; vs += d * d; }
    #pragma unroll
    for (int m = 1; m < 64; m <<= 1) vs += __shfl_xor(vs, m, 64);
    if (lnid == 0) red[wv] = vs;
    __syncthreads();
    if (tid == 0) red[5] = red[0] + red[1] + red[2] + red[3];
    __syncthreads();
    float var = red[5] * (1.f / DMODEL);
    float inv = rsqrtf(var + 1e-5f);

    #pragma unroll
    for (int e = 0; e < 4; ++e) {
        int cc = tid + e * 256;
        out[row * DMODEL + cc] = (x[e] - mu) * inv * gamma[cc] + beta[cc];
    }
}

// ---------------------------------------------------------------------------
extern "C" void kernel_launch(void* const* d_in, const int* in_sizes, int n_in,
                              void* d_out, int out_size, void* d_ws, size_t ws_size,
                              hipStream_t stream)
{
    const float* w     = (const float*)d_in[0];
    const float* r     = (const float*)d_in[1];
    const float* rwb   = (const float*)d_in[2];
    const float* rrb   = (const float*)d_in[3];
    // d_in[4] = attn_mask: deterministically causal-tril, applied analytically.
    const float* Wqkv  = (const float*)d_in[5];
    const float* Wr    = (const float*)d_in[6];
    const float* Wo    = (const float*)d_in[7];
    const float* gamma = (const float*)d_in[8];
    const float* beta  = (const float*)d_in[9];
    float* out = (float*)d_out;

    // workspace layout (86.1 MB total; round-1 high-water was 88.2 MB, OK)
    float* heads = (float*)d_ws;                 // 12,582,912 f  (4096 x 3072)
    float* vec   = heads + 12582912;             //  4,194,304 f  (4096 x 1024)
    float* rkbuf = vec;                          //  overlay: dead before vec written
    short* kb    = (short*)(vec + 4194304);      //  4,194,304 bf16 [bn][j][64]
    short* vTb   = kb + 4194304;                 //  4,194,304 bf16 [bn][64][j]
    short* rkb   = vTb + 4194304;                //  1,114,112 bf16 [1088][1024]
    float* attno = heads;                        //  overlay: heads dead after attn

    // 1) heads = w @ W_qkv
    gemm_kernel<<<dim3(48, 64), 256, 0, stream>>>(w, Wqkv, heads, 4096, 3072, 1024);
    // 2) r_k = r @ W_r  (into vec region, consumed before attention writes vec)
    gemm_kernel<<<dim3(16, 16), 256, 0, stream>>>(r, Wr, rkbuf, 1024, 1024, 1024);
    // 3) bf16 conversions / layouts
    prep_rk<<<544, 256, 0, stream>>>(rkbuf, rkb);
    prep_kv<<<dim3(64, 16), 256, 0, stream>>>(heads, kb, vTb);
    // 4) MFMA flash attention with fused rel-shift
    attn_mfma<<<dim3(16, 64), 256, 0, stream>>>(heads, rkb, kb, vTb, rwb, rrb, vec);
    // 5) attn_out = vec @ W_o  (into heads region overlay)
    gemm_kernel<<<dim3(16, 64), 256, 0, stream>>>(vec, Wo, attno, 4096, 1024, 1024);
    // 6) out = LN(w + attn_out)
    ln_kernel<<<4096, 256, 0, stream>>>(w, attno, gamma, beta, out);
}

// Round 4
// 415.204 us; speedup vs baseline: 3.7847x; 2.1090x over previous
//
#include <hip/hip_runtime.h>
#include <math.h>

constexpr int QLEN_C  = 1024;
constexpr int BSZ_C   = 4;
constexpr int DMODEL  = 1024;
constexpr float SCALE = 0.125f;   // 1/sqrt(64)
constexpr float NEGF  = -1e30f;

typedef __attribute__((ext_vector_type(8))) short bh8;   // 8 bf16 (4 VGPRs)
typedef __attribute__((ext_vector_type(4))) float f32x4; // MFMA acc

__device__ inline short f2bf(float f) {
    union { float f; unsigned u; } v; v.f = f;
    unsigned r = v.u + 0x7FFFu + ((v.u >> 16) & 1u);   // round-to-nearest-even
    return (short)(r >> 16);
}
__device__ inline float bf2f(short s) {
    union { unsigned u; float f; } v;
    v.u = ((unsigned)(unsigned short)s) << 16;
    return v.f;
}
// async global->LDS, 16B per lane. LDS layout must be lane-linear (base+lane*16).
__device__ inline void gload16(const void* g, void* l) {
    __builtin_amdgcn_global_load_lds(
        (__attribute__((address_space(1))) void*)g,
        (__attribute__((address_space(3))) void*)l, 16, 0, 0);
}

// ---------------------------------------------------------------------------
// bf16 MFMA GEMM (m97 structure): C[M,N] = A[M,K] @ BT[N,K]^T
// 128x128 tile, BK=32, 256 thr (4 waves, each a 64x64 quadrant, 4x4 MFMAs).
// Staging via global_load_lds width=16; LDS chunk index == lane order.
// ---------------------------------------------------------------------------
template<bool OUT_BF16>
__global__ __launch_bounds__(256)
void gemm_bf16(const short* __restrict__ A, const short* __restrict__ BT,
               void* __restrict__ C, int M, int N, int K)
{
    constexpr int BK = 32;
    __shared__ alignas(16) short As[128 * BK];   // [m][k], row stride 32 (64B)
    __shared__ alignas(16) short Bs[128 * BK];   // [n][k]

    const int tid = threadIdx.x;
    const int wave = tid >> 6, lane = tid & 63;
    const int quad = lane >> 4, c = lane & 15;
    const int wr = wave >> 1, wc = wave & 1;
    const int row0 = blockIdx.y * 128, col0 = blockIdx.x * 128;

    // staging chunks: 512 x 16B per tile; chunk -> (m=ch>>2, seg=ch&3)
    const int ch0 = wave * 128 + lane, ch1 = ch0 + 64;
    const int m0 = ch0 >> 2, s0 = ch0 & 3;
    const int m1 = ch1 >> 2, s1 = ch1 & 3;

    f32x4 acc[4][4];
    #pragma unroll
    for (int i = 0; i < 4; ++i)
        #pragma unroll
        for (int j = 0; j < 4; ++j) acc[i][j] = (f32x4)0.0f;

    for (int k0 = 0; k0 < K; k0 += BK) {
        gload16(A  + (size_t)(row0 + m0) * K + k0 + s0 * 8, (char*)As + ch0 * 16);
        gload16(A  + (size_t)(row0 + m1) * K + k0 + s1 * 8, (char*)As + ch1 * 16);
        gload16(BT + (size_t)(col0 + m0) * K + k0 + s0 * 8, (char*)Bs + ch0 * 16);
        gload16(BT + (size_t)(col0 + m1) * K + k0 + s1 * 8, (char*)Bs + ch1 * 16);
        __syncthreads();   // drains vmcnt (global_load_lds) before ds_read

        bh8 aF[4], bF[4];
        #pragma unroll
        for (int mi = 0; mi < 4; ++mi)
            aF[mi] = *(const bh8*)&As[(wr * 64 + mi * 16 + c) * BK + quad * 8];
        #pragma unroll
        for (int ni = 0; ni < 4; ++ni)
            bF[ni] = *(const bh8*)&Bs[(wc * 64 + ni * 16 + c) * BK + quad * 8];
        #pragma unroll
        for (int mi = 0; mi < 4; ++mi)
            #pragma unroll
            for (int ni = 0; ni < 4; ++ni)
                acc[mi][ni] = __builtin_amdgcn_mfma_f32_16x16x32_bf16(
                    aF[mi], bF[ni], acc[mi][ni], 0, 0, 0);
        __syncthreads();
    }

    #pragma unroll
    for (int mi = 0; mi < 4; ++mi)
        #pragma unroll
        for (int ni = 0; ni < 4; ++ni)
            #pragma unroll
            for (int r = 0; r < 4; ++r) {
                int orow = row0 + wr * 64 + mi * 16 + quad * 4 + r;
                int ocol = col0 + wc * 64 + ni * 16 + c;
                if (OUT_BF16)
                    ((short*)C)[(size_t)orow * N + ocol] = f2bf(acc[mi][ni][r]);
                else
                    ((float*)C)[(size_t)orow * N + ocol] = acc[mi][ni][r];
            }
}

// ---------------------------------------------------------------------------
// conv_bf16: fp32 -> bf16, 8 elems/thread
// ---------------------------------------------------------------------------
__global__ __launch_bounds__(256)
void conv_bf16(const float* __restrict__ x, short* __restrict__ y)
{
    int idx = (blockIdx.x * 256 + threadIdx.x) * 8;
    bh8 o;
    #pragma unroll
    for (int e = 0; e < 8; ++e) o[e] = f2bf(x[idx + e]);
    *(bh8*)(y + idx) = o;
}

// ---------------------------------------------------------------------------
// transp_conv: BT[n][k] = bf16(B[k][n]); B fp32 [K][N]. 64x64 tiles.
// ---------------------------------------------------------------------------
__global__ __launch_bounds__(256)
void transp_conv(const float* __restrict__ B, short* __restrict__ BT,
                 int K, int N)
{
    __shared__ float tile[64][68];
    const int n0 = blockIdx.x * 64, k0 = blockIdx.y * 64;
    const int t = threadIdx.x;
    const int row = t >> 2, c4 = t & 3;
    const float* src = B + (size_t)(k0 + row) * N + n0 + c4 * 16;
    #pragma unroll
    for (int u = 0; u < 4; ++u) {
        float4 v = *(const float4*)(src + u * 4);
        tile[row][c4 * 16 + u * 4 + 0] = v.x;
        tile[row][c4 * 16 + u * 4 + 1] = v.y;
        tile[row][c4 * 16 + u * 4 + 2] = v.z;
        tile[row][c4 * 16 + u * 4 + 3] = v.w;
    }
    __syncthreads();
    const int nl = t >> 2, kc = t & 3;
    short tmp[16];
    #pragma unroll
    for (int e = 0; e < 16; ++e) tmp[e] = f2bf(tile[kc * 16 + e][nl]);
    short* dst = BT + (size_t)(n0 + nl) * K + k0 + kc * 16;
    *(bh8*)dst = *(bh8*)&tmp[0];
    *(bh8*)(dst + 8) = *(bh8*)&tmp[8];
}

// ---------------------------------------------------------------------------
// prep_kv: headsb bf16 -> kb bf16 [bn][j][64] and vT bf16 [bn][64][j]
// ---------------------------------------------------------------------------
__global__ __launch_bounds__(256)
void prep_kv(const short* __restrict__ headsb, short* __restrict__ kb,
             short* __restrict__ vT)
{
    __shared__ short vtile[64][72];
    const int bn = blockIdx.x, jt = blockIdx.y;
    const int b = bn & 3, n = bn >> 2;
    const int j0 = jt * 64;
    const int t = threadIdx.x;
    const int row = t >> 2, d0 = (t & 3) * 16;

    const short* kp = headsb + ((size_t)(j0 + row) * 4 + b) * 3072 + 1024 + n * 64 + d0;
    const short* vp = kp + 1024;

    bh8 kv0 = *(const bh8*)kp, kv1 = *(const bh8*)(kp + 8);
    bh8 vv0 = *(const bh8*)vp, vv1 = *(const bh8*)(vp + 8);
    short* kdst = kb + ((size_t)bn * 1024 + j0 + row) * 64 + d0;
    *(bh8*)kdst = kv0;
    *(bh8*)(kdst + 8) = kv1;
    #pragma unroll
    for (int e = 0; e < 8; ++e) {
        vtile[row][d0 + e] = vv0[e];
        vtile[row][d0 + 8 + e] = vv1[e];
    }
    __syncthreads();
    const int d = t >> 2, jl0 = (t & 3) * 16;
    short tmp[16];
    #pragma unroll
    for (int e = 0; e < 16; ++e) tmp[e] = vtile[jl0 + e][d];
    short* vdst = vT + ((size_t)bn * 64 + d) * 1024 + j0 + jl0;
    *(bh8*)vdst = *(bh8*)&tmp[0];
    *(bh8*)(vdst + 8) = *(bh8*)&tmp[8];
}

// ---------------------------------------------------------------------------
// MFMA flash attention with fused rel-shift (verified round 3), bf16 I/O.
// ---------------------------------------------------------------------------
__global__ __launch_bounds__(256)
void attn_mfma(const short* __restrict__ headsb, const short* __restrict__ rkb,
               const short* __restrict__ kb, const short* __restrict__ vT,
               const float* __restrict__ rwb, const float* __restrict__ rrb,
               short* __restrict__ vecb)
{
    __shared__ alignas(16) float sBt[4][16 * 97];
    __shared__ alignas(16) short sP[4][16 * 80];

    const int tid = threadIdx.x;
    const int wave = tid >> 6, lane = tid & 63;
    const int quad = lane >> 4, c = lane & 15;
    const int i0 = blockIdx.x * 64;
    const int bn = blockIdx.y;
    const int b = bn & 3, n = bn >> 2;
    const int rowsbase = i0 + wave * 16;

    // Q fragments with both biases (A-layout: m=c, k=quad*8+e+32*ks)
    bh8 aAC[2], aBD[2];
    const int dq = n * 64 + quad * 8;
    #pragma unroll
    for (int ks = 0; ks < 2; ++ks) {
        const short* qp = headsb + ((size_t)(rowsbase + c) * 4 + b) * 3072 + dq + 32 * ks;
        bh8 q8 = *(const bh8*)qp;
        #pragma unroll
        for (int e = 0; e < 8; ++e) {
            float qv = bf2f(q8[e]);
            aAC[ks][e] = f2bf(qv + rwb[dq + 32 * ks + e]);
            aBD[ks][e] = f2bf(qv + rrb[dq + 32 * ks + e]);
        }
    }

    f32x4 oacc[4];
    #pragma unroll
    for (int dt = 0; dt < 4; ++dt) oacc[dt] = (f32x4)0.0f;
    float m_r[4] = {-3.0e38f, -3.0e38f, -3.0e38f, -3.0e38f};
    float l_r[4] = {0.f, 0.f, 0.f, 0.f};

    float* BtL = &sBt[wave][0];
    short* PL  = &sP[wave][0];
    const short* kbp = kb + (size_t)bn * 1024 * 64;
    const short* vtp = vT + (size_t)bn * 64 * 1024;

    for (int j0 = 0; j0 <= i0 + 63; j0 += 64) {
        // ---- Bt = (q+rrb) . rk-window (5 column tiles of 16) ----
        const int jrw0 = 1008 - rowsbase + j0;
        f32x4 bt[5];
        #pragma unroll
        for (int tt = 0; tt < 5; ++tt) {
            bt[tt] = (f32x4)0.0f;
            const short* rp = rkb + (size_t)(jrw0 + c + 16 * tt) * 1024 + n * 64 + quad * 8;
            #pragma unroll
            for (int ks = 0; ks < 2; ++ks) {
                bh8 bf = *(const bh8*)(rp + 32 * ks);
                bt[tt] = __builtin_amdgcn_mfma_f32_16x16x32_bf16(aBD[ks], bf, bt[tt], 0, 0, 0);
            }
        }
        // sheared write: value Bt[row][t] -> slot row*97 + row + t
        #pragma unroll
        for (int tt = 0; tt < 5; ++tt)
            #pragma unroll
            for (int r = 0; r < 4; ++r) {
                int row = quad * 4 + r;
                BtL[row * 97 + row + c + 16 * tt] = bt[tt][r];
            }

        // ---- AC = (q+rwb) . K^T ----
        f32x4 ac[4];
        #pragma unroll
        for (int jt = 0; jt < 4; ++jt) {
            ac[jt] = (f32x4)0.0f;
            const short* kp = kbp + (size_t)(j0 + c + 16 * jt) * 64 + quad * 8;
            #pragma unroll
            for (int ks = 0; ks < 2; ++ks) {
                bh8 bf = *(const bh8*)(kp + 32 * ks);
                ac[jt] = __builtin_amdgcn_mfma_f32_16x16x32_bf16(aAC[ks], bf, ac[jt], 0, 0, 0);
            }
        }

        __syncthreads();   // Bt writes visible before gather

        // ---- gather + mask + online softmax (row = quad*4+r) ----
        float al[4];
        #pragma unroll
        for (int r = 0; r < 4; ++r) {
            const int row = quad * 4 + r;
            const int gi = rowsbase + row;
            float s[4];
            float mx = -3.0e38f;
            #pragma unroll
            for (int jt = 0; jt < 4; ++jt) {
                int gj = j0 + c + 16 * jt;
                float v = SCALE * (ac[jt][r] + BtL[row * 97 + c + 16 * jt + 15]);
                if (gj > gi) v = NEGF;
                s[jt] = v;
                mx = fmaxf(mx, v);
            }
            #pragma unroll
            for (int msk = 1; msk < 16; msk <<= 1)
                mx = fmaxf(mx, __shfl_xor(mx, msk, 64));
            float mnew = fmaxf(m_r[r], mx);
            al[r] = __expf(m_r[r] - mnew);
            m_r[r] = mnew;
            float ps = 0.f;
            #pragma unroll
            for (int jt = 0; jt < 4; ++jt) {
                float p = __expf(s[jt] - mnew);
                PL[row * 80 + c + 16 * jt] = f2bf(p);
                ps += p;
            }
            #pragma unroll
            for (int msk = 1; msk < 16; msk <<= 1)
                ps += __shfl_xor(ps, msk, 64);
            l_r[r] = l_r[r] * al[r] + ps;
            #pragma unroll
            for (int dt = 0; dt < 4; ++dt) oacc[dt][r] *= al[r];
        }

        __syncthreads();   // P writes visible before A-frag reads

        // ---- PV: O += P @ V ----
        bh8 aP[2];
        #pragma unroll
        for (int ks = 0; ks < 2; ++ks)
            aP[ks] = *(const bh8*)(PL + c * 80 + 32 * ks + quad * 8);
        #pragma unroll
        for (int dt = 0; dt < 4; ++dt) {
            const short* vp = vtp + (size_t)(c + 16 * dt) * 1024 + j0 + quad * 8;
            #pragma unroll
            for (int ks = 0; ks < 2; ++ks) {
                bh8 bf = *(const bh8*)(vp + 32 * ks);
                oacc[dt] = __builtin_amdgcn_mfma_f32_16x16x32_bf16(aP[ks], bf, oacc[dt], 0, 0, 0);
            }
        }
    }

    // epilogue: normalize, store vecb[i][b][n*64+d] bf16
    #pragma unroll
    for (int r = 0; r < 4; ++r) {
        float rinv = 1.f / l_r[r];
        int gi = rowsbase + quad * 4 + r;
        short* op = vecb + ((size_t)gi * 4 + b) * 1024 + n * 64;
        #pragma unroll
        for (int dt = 0; dt < 4; ++dt)
            op[c + 16 * dt] = f2bf(oacc[dt][r] * rinv);
    }
}

// ---------------------------------------------------------------------------
// out = LayerNorm(w + attn_out) — one block per row (verified round 1)
// ---------------------------------------------------------------------------
__global__ __launch_bounds__(256)
void ln_kernel(const float* __restrict__ w, const float* __restrict__ attn,
               const float* __restrict__ gamma, const float* __restrict__ beta,
               float* __restrict__ out)
{
    const int row = blockIdx.x;
    const int tid = threadIdx.x;
    const float* xw = w + row * DMODEL;
    const float* xa = attn + row * DMODEL;

    float x[4];
    float s = 0.f;
    #pragma unroll
    for (int e = 0; e < 4; ++e) {
        int cc = tid + e * 256;
        x[e] = xw[cc] + xa[cc];
        s += x[e];
    }
    __shared__ float red[6];
    #pragma unroll
    for (int m = 1; m < 64; m <<= 1) s += __shfl_xor(s, m, 64);
    int wv = tid >> 6, lnid = tid & 63;
    if (lnid == 0) red[wv] = s;
    __syncthreads();
    if (tid == 0) red[4] = red[0] + red[1] + red[2] + red[3];
    __syncthreads();
    float mu = red[4] * (1.f / DMODEL);

    float vs = 0.f;
    #pragma unroll
    for (int e = 0; e < 4; ++e) { float d = x[e] - mu; vs += d * d; }
    #pragma unroll
    for (int m = 1; m < 64; m <<= 1) vs += __shfl_xor(vs, m, 64);
    if (lnid == 0) red[wv] = vs;
    __syncthreads();
    if (tid == 0) red[5] = red[0] + red[1] + red[2] + red[3];
    __syncthreads();
    float var = red[5] * (1.f / DMODEL);
    float inv = rsqrtf(var + 1e-5f);

    #pragma unroll
    for (int e = 0; e < 4; ++e) {
        int cc = tid + e * 256;
        out[row * DMODEL + cc] = (x[e] - mu) * inv * gamma[cc] + beta[cc];
    }
}

// ---------------------------------------------------------------------------
extern "C" void kernel_launch(void* const* d_in, const int* in_sizes, int n_in,
                              void* d_out, int out_size, void* d_ws, size_t ws_size,
                              hipStream_t stream)
{
    const float* w     = (const float*)d_in[0];
    const float* r     = (const float*)d_in[1];
    const float* rwb   = (const float*)d_in[2];
    const float* rrb   = (const float*)d_in[3];
    // d_in[4] = attn_mask: deterministically causal-tril, applied analytically.
    const float* Wqkv  = (const float*)d_in[5];
    const float* Wr    = (const float*)d_in[6];
    const float* Wo    = (const float*)d_in[7];
    const float* gamma = (const float*)d_in[8];
    const float* beta  = (const float*)d_in[9];
    float* out = (float*)d_out;

    // workspace: 73.5 MB of shorts (+ attno overlays headsb)
    short* headsb = (short*)d_ws;                 // 12,582,912  [4096][3072] bf16
    short* wb     = headsb + 12582912;            //  4,194,304  [4096][1024]
    short* WqkvT  = wb + 4194304;                 //  3,145,728  [3072][1024]
    short* rb     = WqkvT + 3145728;              //  1,048,576  [1024][1024]
    short* WrT    = rb + 1048576;                 //  1,048,576
    short* WoT    = WrT + 1048576;                //  1,048,576
    short* rkb    = WoT + 1048576;                //  1,114,112  [1088][1024]
    short* kb     = rkb + 1114112;                //  4,194,304  [bn][j][64]
    short* vTb    = kb + 4194304;                 //  4,194,304  [bn][64][j]
    short* vecb   = vTb + 4194304;                //  4,194,304  [4096][1024]
    float* attno  = (float*)headsb;               //  overlay: headsb dead after attn

    // 0) dtype prep
    conv_bf16<<<2048, 256, 0, stream>>>(w, wb);
    conv_bf16<<<512, 256, 0, stream>>>(r, rb);
    transp_conv<<<dim3(48, 16), 256, 0, stream>>>(Wqkv, WqkvT, 1024, 3072);
    transp_conv<<<dim3(16, 16), 256, 0, stream>>>(Wr, WrT, 1024, 1024);
    transp_conv<<<dim3(16, 16), 256, 0, stream>>>(Wo, WoT, 1024, 1024);
    // 1) heads = w @ W_qkv  (bf16 out)
    gemm_bf16<true><<<dim3(24, 32), 256, 0, stream>>>(wb, WqkvT, headsb, 4096, 3072, 1024);
    // 2) r_k = r @ W_r  (bf16 out, rows 0..1023 of rkb; pad rows zeroed)
    gemm_bf16<true><<<dim3(8, 8), 256, 0, stream>>>(rb, WrT, rkb, 1024, 1024, 1024);
    hipMemsetAsync(rkb + 1024 * 1024, 0, 64 * 1024 * sizeof(short), stream);
    // 3) K/V layouts
    prep_kv<<<dim3(64, 16), 256, 0, stream>>>(headsb, kb, vTb);
    // 4) MFMA flash attention with fused rel-shift
    attn_mfma<<<dim3(16, 64), 256, 0, stream>>>(headsb, rkb, kb, vTb, rwb, rrb, vecb);
    // 5) attn_out = vec @ W_o  (fp32 out, overlays headsb)
    gemm_bf16<false><<<dim3(8, 32), 256, 0, stream>>>(vecb, WoT, attno, 4096, 1024, 1024);
    // 6) out = LN(w + attn_out)
    ln_kernel<<<4096, 256, 0, stream>>>(w, attno, gamma, beta, out);
}

// Round 5
// 320.352 us; speedup vs baseline: 4.9053x; 1.2961x over previous
//
#include <hip/hip_runtime.h>
#include <math.h>

constexpr int QLEN_C  = 1024;
constexpr int BSZ_C   = 4;
constexpr int DMODEL  = 1024;
constexpr float SCALE = 0.125f;   // 1/sqrt(64)
constexpr float NEGF  = -1e30f;

typedef __attribute__((ext_vector_type(8))) short bh8;   // 8 bf16 (4 VGPRs)
typedef __attribute__((ext_vector_type(4))) float f32x4; // MFMA acc

__device__ inline short f2bf(float f) {
    union { float f; unsigned u; } v; v.f = f;
    unsigned r = v.u + 0x7FFFu + ((v.u >> 16) & 1u);   // round-to-nearest-even
    return (short)(r >> 16);
}
__device__ inline float bf2f(short s) {
    union { unsigned u; float f; } v;
    v.u = ((unsigned)(unsigned short)s) << 16;
    return v.f;
}
// async global->LDS, 16B per lane. LDS layout must be lane-linear (base+lane*16).
__device__ inline void gload16(const void* g, void* l) {
    __builtin_amdgcn_global_load_lds(
        (__attribute__((address_space(1))) void*)g,
        (__attribute__((address_space(3))) void*)l, 16, 0, 0);
}
// Per-wave LDS fence: prior ds_writes retired before subsequent ds_reads issue.
// lgkmcnt(0) only -- vmcnt (global register prefetch) stays in flight.
// 0xC07F = vmcnt 63 (no wait), expcnt 7 (no wait), lgkmcnt 0 (full drain).
__device__ inline void wave_lds_fence() {
    __builtin_amdgcn_sched_barrier(0);
    __builtin_amdgcn_s_waitcnt(0xC07F);
    __builtin_amdgcn_sched_barrier(0);
}

// ---------------------------------------------------------------------------
// bf16 MFMA GEMM (m97 structure, verified round 4): C[M,N] = A[M,K] @ BT[N,K]^T
// ---------------------------------------------------------------------------
template<bool OUT_BF16>
__global__ __launch_bounds__(256)
void gemm_bf16(const short* __restrict__ A, const short* __restrict__ BT,
               void* __restrict__ C, int M, int N, int K)
{
    constexpr int BK = 32;
    __shared__ alignas(16) short As[128 * BK];
    __shared__ alignas(16) short Bs[128 * BK];

    const int tid = threadIdx.x;
    const int wave = tid >> 6, lane = tid & 63;
    const int quad = lane >> 4, c = lane & 15;
    const int wr = wave >> 1, wc = wave & 1;
    const int row0 = blockIdx.y * 128, col0 = blockIdx.x * 128;

    const int ch0 = wave * 128 + lane, ch1 = ch0 + 64;
    const int m0 = ch0 >> 2, s0 = ch0 & 3;
    const int m1 = ch1 >> 2, s1 = ch1 & 3;

    f32x4 acc[4][4];
    #pragma unroll
    for (int i = 0; i < 4; ++i)
        #pragma unroll
        for (int j = 0; j < 4; ++j) acc[i][j] = (f32x4)0.0f;

    for (int k0 = 0; k0 < K; k0 += BK) {
        gload16(A  + (size_t)(row0 + m0) * K + k0 + s0 * 8, (char*)As + ch0 * 16);
        gload16(A  + (size_t)(row0 + m1) * K + k0 + s1 * 8, (char*)As + ch1 * 16);
        gload16(BT + (size_t)(col0 + m0) * K + k0 + s0 * 8, (char*)Bs + ch0 * 16);
        gload16(BT + (size_t)(col0 + m1) * K + k0 + s1 * 8, (char*)Bs + ch1 * 16);
        __syncthreads();

        bh8 aF[4], bF[4];
        #pragma unroll
        for (int mi = 0; mi < 4; ++mi)
            aF[mi] = *(const bh8*)&As[(wr * 64 + mi * 16 + c) * BK + quad * 8];
        #pragma unroll
        for (int ni = 0; ni < 4; ++ni)
            bF[ni] = *(const bh8*)&Bs[(wc * 64 + ni * 16 + c) * BK + quad * 8];
        #pragma unroll
        for (int mi = 0; mi < 4; ++mi)
            #pragma unroll
            for (int ni = 0; ni < 4; ++ni)
                acc[mi][ni] = __builtin_amdgcn_mfma_f32_16x16x32_bf16(
                    aF[mi], bF[ni], acc[mi][ni], 0, 0, 0);
        __syncthreads();
    }

    #pragma unroll
    for (int mi = 0; mi < 4; ++mi)
        #pragma unroll
        for (int ni = 0; ni < 4; ++ni)
            #pragma unroll
            for (int r = 0; r < 4; ++r) {
                int orow = row0 + wr * 64 + mi * 16 + quad * 4 + r;
                int ocol = col0 + wc * 64 + ni * 16 + c;
                if (OUT_BF16)
                    ((short*)C)[(size_t)orow * N + ocol] = f2bf(acc[mi][ni][r]);
                else
                    ((float*)C)[(size_t)orow * N + ocol] = acc[mi][ni][r];
            }
}

// ---------------------------------------------------------------------------
__global__ __launch_bounds__(256)
void conv_bf16(const float* __restrict__ x, short* __restrict__ y)
{
    int idx = (blockIdx.x * 256 + threadIdx.x) * 8;
    bh8 o;
    #pragma unroll
    for (int e = 0; e < 8; ++e) o[e] = f2bf(x[idx + e]);
    *(bh8*)(y + idx) = o;
}

// ---------------------------------------------------------------------------
__global__ __launch_bounds__(256)
void transp_conv(const float* __restrict__ B, short* __restrict__ BT,
                 int K, int N)
{
    __shared__ float tile[64][68];
    const int n0 = blockIdx.x * 64, k0 = blockIdx.y * 64;
    const int t = threadIdx.x;
    const int row = t >> 2, c4 = t & 3;
    const float* src = B + (size_t)(k0 + row) * N + n0 + c4 * 16;
    #pragma unroll
    for (int u = 0; u < 4; ++u) {
        float4 v = *(const float4*)(src + u * 4);
        tile[row][c4 * 16 + u * 4 + 0] = v.x;
        tile[row][c4 * 16 + u * 4 + 1] = v.y;
        tile[row][c4 * 16 + u * 4 + 2] = v.z;
        tile[row][c4 * 16 + u * 4 + 3] = v.w;
    }
    __syncthreads();
    const int nl = t >> 2, kc = t & 3;
    short tmp[16];
    #pragma unroll
    for (int e = 0; e < 16; ++e) tmp[e] = f2bf(tile[kc * 16 + e][nl]);
    short* dst = BT + (size_t)(n0 + nl) * K + k0 + kc * 16;
    *(bh8*)dst = *(bh8*)&tmp[0];
    *(bh8*)(dst + 8) = *(bh8*)&tmp[8];
}

// ---------------------------------------------------------------------------
__global__ __launch_bounds__(256)
void prep_kv(const short* __restrict__ headsb, short* __restrict__ kb,
             short* __restrict__ vT)
{
    __shared__ short vtile[64][72];
    const int bn = blockIdx.x, jt = blockIdx.y;
    const int b = bn & 3, n = bn >> 2;
    const int j0 = jt * 64;
    const int t = threadIdx.x;
    const int row = t >> 2, d0 = (t & 3) * 16;

    const short* kp = headsb + ((size_t)(j0 + row) * 4 + b) * 3072 + 1024 + n * 64 + d0;
    const short* vp = kp + 1024;

    bh8 kv0 = *(const bh8*)kp, kv1 = *(const bh8*)(kp + 8);
    bh8 vv0 = *(const bh8*)vp, vv1 = *(const bh8*)(vp + 8);
    short* kdst = kb + ((size_t)bn * 1024 + j0 + row) * 64 + d0;
    *(bh8*)kdst = kv0;
    *(bh8*)(kdst + 8) = kv1;
    #pragma unroll
    for (int e = 0; e < 8; ++e) {
        vtile[row][d0 + e] = vv0[e];
        vtile[row][d0 + 8 + e] = vv1[e];
    }
    __syncthreads();
    const int d = t >> 2, jl0 = (t & 3) * 16;
    short tmp[16];
    #pragma unroll
    for (int e = 0; e < 16; ++e) tmp[e] = vtile[jl0 + e][d];
    short* vdst = vT + ((size_t)bn * 64 + d) * 1024 + j0 + jl0;
    *(bh8*)vdst = *(bh8*)&tmp[0];
    *(bh8*)(vdst + 8) = *(bh8*)&tmp[8];
}

// ---------------------------------------------------------------------------
// Wave-autonomous MFMA flash attention with fused rel-shift.
// Grid (8, 64) x 256 thr. Wave w of block (pair,bn) owns sub-tile pair
// {sA=4*pair+w, sB=63-sA} (16 Q rows each, processed sequentially) -> every
// wave does exactly 17 j-units: perfect CU balance. No __syncthreads: LDS is
// per-wave private; phase boundaries use lgkmcnt(0)-only fences so the
// rk/K register prefetch for unit u+1 stays in flight across phases.
// ---------------------------------------------------------------------------
__global__ __launch_bounds__(256)
void attn_mfma(const short* __restrict__ headsb, const short* __restrict__ rkb,
               const short* __restrict__ kb, const short* __restrict__ vT,
               const float* __restrict__ rwb, const float* __restrict__ rrb,
               short* __restrict__ vecb)
{
    __shared__ alignas(16) float sBt[4][16 * 97];
    __shared__ alignas(16) short sP[4][16 * 80];

    const int tid = threadIdx.x;
    const int wave = tid >> 6, lane = tid & 63;
    const int quad = lane >> 4, c = lane & 15;

    // XCD-aware swizzle: same head n lands on one XCD (speed heuristic only)
    const int F = blockIdx.x + 8 * blockIdx.y;   // 0..511
    const int n = (F & 7) + ((F >> 3) >= 32 ? 8 : 0);
    const int rem = (F >> 3) & 31;
    const int b = rem & 3;
    const int pair = rem >> 2;                   // 0..7
    const int sA = 4 * pair + wave;              // sub-tile 0..31
    const int sB = 63 - sA;                      // partner 32..63
    const int nU_A = pair + 1;                   // j-units for strip A
    const int bn = n * 4 + b;

    const int dq = n * 64 + quad * 8;
    float* BtL = &sBt[wave][0];
    short* PL  = &sP[wave][0];
    const short* kbp = kb + (size_t)bn * 1024 * 64;
    const short* vtp = vT + (size_t)bn * 64 * 1024;

    bh8 aAC[2], aBD[2];
    auto load_q = [&](int rb) {
        #pragma unroll
        for (int ks = 0; ks < 2; ++ks) {
            const short* qp = headsb + ((size_t)(rb + c) * 4 + b) * 3072 + dq + 32 * ks;
            bh8 q8 = *(const bh8*)qp;
            #pragma unroll
            for (int e = 0; e < 8; ++e) {
                float qv = bf2f(q8[e]);
                aAC[ks][e] = f2bf(qv + rwb[dq + 32 * ks + e]);
                aBD[ks][e] = f2bf(qv + rrb[dq + 32 * ks + e]);
            }
        }
    };

    bh8 rkv[10], kbv[8];
    auto pf = [&](int rb, int j0) {
        const int jrw0 = 1008 - rb + j0;
        #pragma unroll
        for (int tt = 0; tt < 5; ++tt) {
            const short* rp = rkb + (size_t)(jrw0 + c + 16 * tt) * 1024 + dq;
            rkv[2 * tt]     = *(const bh8*)rp;
            rkv[2 * tt + 1] = *(const bh8*)(rp + 32);
        }
        #pragma unroll
        for (int jt = 0; jt < 4; ++jt) {
            const short* kp = kbp + (size_t)(j0 + c + 16 * jt) * 64 + quad * 8;
            kbv[2 * jt]     = *(const bh8*)kp;
            kbv[2 * jt + 1] = *(const bh8*)(kp + 32);
        }
    };

    f32x4 oacc[4];
    float m_r[4], l_r[4];
    #pragma unroll
    for (int dt = 0; dt < 4; ++dt) oacc[dt] = (f32x4)0.0f;
    #pragma unroll
    for (int r = 0; r < 4; ++r) { m_r[r] = -3.0e38f; l_r[r] = 0.f; }

    auto epi = [&](int rb) {
        #pragma unroll
        for (int r = 0; r < 4; ++r) {
            float rinv = 1.f / l_r[r];
            int gi = rb + quad * 4 + r;
            short* op = vecb + ((size_t)gi * 4 + b) * 1024 + n * 64;
            #pragma unroll
            for (int dt = 0; dt < 4; ++dt)
                op[c + 16 * dt] = f2bf(oacc[dt][r] * rinv);
        }
    };

    int rb = sA * 16;
    load_q(rb);
    pf(rb, 0);
    int j0 = 0;

    for (int u = 0; u < 17; ++u) {
        // V fragments for current unit (consumed after softmax - long window)
        bh8 vvv[8];
        #pragma unroll
        for (int dt = 0; dt < 4; ++dt) {
            const short* vp = vtp + (size_t)(c + 16 * dt) * 1024 + j0 + quad * 8;
            vvv[2 * dt]     = *(const bh8*)vp;
            vvv[2 * dt + 1] = *(const bh8*)(vp + 32);
        }

        // ---- phase A: Bt and AC MFMAs from prefetched fragments ----
        f32x4 bt[5];
        #pragma unroll
        for (int tt = 0; tt < 5; ++tt) {
            bt[tt] = (f32x4)0.0f;
            bt[tt] = __builtin_amdgcn_mfma_f32_16x16x32_bf16(aBD[0], rkv[2 * tt], bt[tt], 0, 0, 0);
            bt[tt] = __builtin_amdgcn_mfma_f32_16x16x32_bf16(aBD[1], rkv[2 * tt + 1], bt[tt], 0, 0, 0);
        }
        f32x4 ac[4];
        #pragma unroll
        for (int jt = 0; jt < 4; ++jt) {
            ac[jt] = (f32x4)0.0f;
            ac[jt] = __builtin_amdgcn_mfma_f32_16x16x32_bf16(aAC[0], kbv[2 * jt], ac[jt], 0, 0, 0);
            ac[jt] = __builtin_amdgcn_mfma_f32_16x16x32_bf16(aAC[1], kbv[2 * jt + 1], ac[jt], 0, 0, 0);
        }

        // ---- issue prefetch for next unit (stays in flight across fences) ----
        if (u < 16) {
            int nrb = rb, nj0 = j0 + 64;
            if (u + 1 == nU_A) { nrb = sB * 16; nj0 = 0; }
            pf(nrb, nj0);
        }

        // ---- sheared Bt write: (row,t) -> slot row*97 + row + t ----
        #pragma unroll
        for (int tt = 0; tt < 5; ++tt)
            #pragma unroll
            for (int r = 0; r < 4; ++r) {
                int row = quad * 4 + r;
                BtL[row * 97 + row + c + 16 * tt] = bt[tt][r];
            }

        wave_lds_fence();   // Bt writes -> gather reads (same wave)

        // ---- gather + mask + online softmax ----
        float al[4];
        #pragma unroll
        for (int r = 0; r < 4; ++r) {
            const int row = quad * 4 + r;
            const int gi = rb + row;
            float s[4];
            float mx = -3.0e38f;
            #pragma unroll
            for (int jt = 0; jt < 4; ++jt) {
                int gj = j0 + c + 16 * jt;
                float v = SCALE * (ac[jt][r] + BtL[row * 97 + c + 16 * jt + 15]);
                if (gj > gi) v = NEGF;
                s[jt] = v;
                mx = fmaxf(mx, v);
            }
            #pragma unroll
            for (int msk = 1; msk < 16; msk <<= 1)
                mx = fmaxf(mx, __shfl_xor(mx, msk, 64));
            float mnew = fmaxf(m_r[r], mx);
            al[r] = __expf(m_r[r] - mnew);
            m_r[r] = mnew;
            float ps = 0.f;
            #pragma unroll
            for (int jt = 0; jt < 4; ++jt) {
                float p = __expf(s[jt] - mnew);
                PL[row * 80 + c + 16 * jt] = f2bf(p);
                ps += p;
            }
            #pragma unroll
            for (int msk = 1; msk < 16; msk <<= 1)
                ps += __shfl_xor(ps, msk, 64);
            l_r[r] = l_r[r] * al[r] + ps;
            #pragma unroll
            for (int dt = 0; dt < 4; ++dt) oacc[dt][r] *= al[r];
        }

        wave_lds_fence();   // P writes -> aP reads (same wave)

        // ---- PV: O += P @ V ----
        bh8 aP[2];
        #pragma unroll
        for (int ks = 0; ks < 2; ++ks)
            aP[ks] = *(const bh8*)(PL + c * 80 + 32 * ks + quad * 8);
        #pragma unroll
        for (int dt = 0; dt < 4; ++dt) {
            oacc[dt] = __builtin_amdgcn_mfma_f32_16x16x32_bf16(aP[0], vvv[2 * dt], oacc[dt], 0, 0, 0);
            oacc[dt] = __builtin_amdgcn_mfma_f32_16x16x32_bf16(aP[1], vvv[2 * dt + 1], oacc[dt], 0, 0, 0);
        }

        wave_lds_fence();   // aP reads done before next unit's Bt/P overwrites

        // ---- strip switch ----
        if (u + 1 == nU_A) {
            epi(rb);
            #pragma unroll
            for (int dt = 0; dt < 4; ++dt) oacc[dt] = (f32x4)0.0f;
            #pragma unroll
            for (int r = 0; r < 4; ++r) { m_r[r] = -3.0e38f; l_r[r] = 0.f; }
            rb = sB * 16;
            load_q(rb);
            j0 = 0;
        } else {
            j0 += 64;
        }
    }
    epi(rb);
}

// ---------------------------------------------------------------------------
__global__ __launch_bounds__(256)
void ln_kernel(const float* __restrict__ w, const float* __restrict__ attn,
               const float* __restrict__ gamma, const float* __restrict__ beta,
               float* __restrict__ out)
{
    const int row = blockIdx.x;
    const int tid = threadIdx.x;
    const float* xw = w + row * DMODEL;
    const float* xa = attn + row * DMODEL;

    float x[4];
    float s = 0.f;
    #pragma unroll
    for (int e = 0; e < 4; ++e) {
        int cc = tid + e * 256;
        x[e] = xw[cc] + xa[cc];
        s += x[e];
    }
    __shared__ float red[6];
    #pragma unroll
    for (int m = 1; m < 64; m <<= 1) s += __shfl_xor(s, m, 64);
    int wv = tid >> 6, lnid = tid & 63;
    if (lnid == 0) red[wv] = s;
    __syncthreads();
    if (tid == 0) red[4] = red[0] + red[1] + red[2] + red[3];
    __syncthreads();
    float mu = red[4] * (1.f / DMODEL);

    float vs = 0.f;
    #pragma unroll
    for (int e = 0; e < 4; ++e) { float d = x[e] - mu; vs += d * d; }
    #pragma unroll
    for (int m = 1; m < 64; m <<= 1) vs += __shfl_xor(vs, m, 64);
    if (lnid == 0) red[wv] = vs;
    __syncthreads();
    if (tid == 0) red[5] = red[0] + red[1] + red[2] + red[3];
    __syncthreads();
    float var = red[5] * (1.f / DMODEL);
    float inv = rsqrtf(var + 1e-5f);

    #pragma unroll
    for (int e = 0; e < 4; ++e) {
        int cc = tid + e * 256;
        out[row * DMODEL + cc] = (x[e] - mu) * inv * gamma[cc] + beta[cc];
    }
}

// ---------------------------------------------------------------------------
extern "C" void kernel_launch(void* const* d_in, const int* in_sizes, int n_in,
                              void* d_out, int out_size, void* d_ws, size_t ws_size,
                              hipStream_t stream)
{
    const float* w     = (const float*)d_in[0];
    const float* r     = (const float*)d_in[1];
    const float* rwb   = (const float*)d_in[2];
    const float* rrb   = (const float*)d_in[3];
    // d_in[4] = attn_mask: deterministically causal-tril, applied analytically.
    const float* Wqkv  = (const float*)d_in[5];
    const float* Wr    = (const float*)d_in[6];
    const float* Wo    = (const float*)d_in[7];
    const float* gamma = (const float*)d_in[8];
    const float* beta  = (const float*)d_in[9];
    float* out = (float*)d_out;

    short* headsb = (short*)d_ws;                 // 12,582,912  [4096][3072] bf16
    short* wb     = headsb + 12582912;            //  4,194,304  [4096][1024]
    short* WqkvT  = wb + 4194304;                 //  3,145,728  [3072][1024]
    short* rb     = WqkvT + 3145728;              //  1,048,576  [1024][1024]
    short* WrT    = rb + 1048576;                 //  1,048,576
    short* WoT    = WrT + 1048576;                //  1,048,576
    short* rkb    = WoT + 1048576;                //  1,114,112  [1088][1024]
    short* kb     = rkb + 1114112;                //  4,194,304  [bn][j][64]
    short* vTb    = kb + 4194304;                 //  4,194,304  [bn][64][j]
    short* vecb   = vTb + 4194304;                //  4,194,304  [4096][1024]
    float* attno  = (float*)headsb;               //  overlay: headsb dead after attn

    conv_bf16<<<2048, 256, 0, stream>>>(w, wb);
    conv_bf16<<<512, 256, 0, stream>>>(r, rb);
    transp_conv<<<dim3(48, 16), 256, 0, stream>>>(Wqkv, WqkvT, 1024, 3072);
    transp_conv<<<dim3(16, 16), 256, 0, stream>>>(Wr, WrT, 1024, 1024);
    transp_conv<<<dim3(16, 16), 256, 0, stream>>>(Wo, WoT, 1024, 1024);
    gemm_bf16<true><<<dim3(24, 32), 256, 0, stream>>>(wb, WqkvT, headsb, 4096, 3072, 1024);
    gemm_bf16<true><<<dim3(8, 8), 256, 0, stream>>>(rb, WrT, rkb, 1024, 1024, 1024);
    hipMemsetAsync(rkb + 1024 * 1024, 0, 64 * 1024 * sizeof(short), stream);
    prep_kv<<<dim3(64, 16), 256, 0, stream>>>(headsb, kb, vTb);
    attn_mfma<<<dim3(8, 64), 256, 0, stream>>>(headsb, rkb, kb, vTb, rwb, rrb, vecb);
    gemm_bf16<false><<<dim3(8, 32), 256, 0, stream>>>(vecb, WoT, attno, 4096, 1024, 1024);
    ln_kernel<<<4096, 256, 0, stream>>>(w, attno, gamma, beta, out);
}

// Round 7
// 320.284 us; speedup vs baseline: 4.9063x; 1.0002x over previous
//
#include <hip/hip_runtime.h>
#include <math.h>

constexpr int QLEN_C  = 1024;
constexpr int BSZ_C   = 4;
constexpr int DMODEL  = 1024;
constexpr float SCALE = 0.125f;   // 1/sqrt(64)
constexpr float NEGF  = -1e30f;

typedef __attribute__((ext_vector_type(8))) short bh8;   // 8 bf16 (4 VGPRs)
typedef __attribute__((ext_vector_type(4))) float f32x4; // MFMA acc

__device__ inline short f2bf(float f) {
    union { float f; unsigned u; } v; v.f = f;
    unsigned r = v.u + 0x7FFFu + ((v.u >> 16) & 1u);   // round-to-nearest-even
    return (short)(r >> 16);
}
__device__ inline float bf2f(short s) {
    union { unsigned u; float f; } v;
    v.u = ((unsigned)(unsigned short)s) << 16;
    return v.f;
}
// async global->LDS, 16B per lane. LDS layout must be lane-linear (base+lane*16).
__device__ inline void gload16(const void* g, void* l) {
    __builtin_amdgcn_global_load_lds(
        (__attribute__((address_space(1))) void*)g,
        (__attribute__((address_space(3))) void*)l, 16, 0, 0);
}
// Per-wave LDS fence (HW-validated round 5): prior ds_writes retired before
// subsequent ds_reads issue; vmcnt prefetch stays in flight.
// 0xC07F = vmcnt 63 (no wait), expcnt 7 (no wait), lgkmcnt 0 (full drain).
__device__ inline void wave_lds_fence() {
    __builtin_amdgcn_sched_barrier(0);
    __builtin_amdgcn_s_waitcnt(0xC07F);
    __builtin_amdgcn_sched_barrier(0);
}

// ---------------------------------------------------------------------------
// bf16 MFMA GEMM (m97 structure, verified round 4): C[M,N] = A[M,K] @ BT[N,K]^T
// ---------------------------------------------------------------------------
template<bool OUT_BF16>
__global__ __launch_bounds__(256)
void gemm_bf16(const short* __restrict__ A, const short* __restrict__ BT,
               void* __restrict__ C, int M, int N, int K)
{
    constexpr int BK = 32;
    __shared__ alignas(16) short As[128 * BK];
    __shared__ alignas(16) short Bs[128 * BK];

    const int tid = threadIdx.x;
    const int wave = tid >> 6, lane = tid & 63;
    const int quad = lane >> 4, c = lane & 15;
    const int wr = wave >> 1, wc = wave & 1;
    const int row0 = blockIdx.y * 128, col0 = blockIdx.x * 128;

    const int ch0 = wave * 128 + lane, ch1 = ch0 + 64;
    const int m0 = ch0 >> 2, s0 = ch0 & 3;
    const int m1 = ch1 >> 2, s1 = ch1 & 3;

    f32x4 acc[4][4];
    #pragma unroll
    for (int i = 0; i < 4; ++i)
        #pragma unroll
        for (int j = 0; j < 4; ++j) acc[i][j] = (f32x4)0.0f;

    for (int k0 = 0; k0 < K; k0 += BK) {
        gload16(A  + (size_t)(row0 + m0) * K + k0 + s0 * 8, (char*)As + ch0 * 16);
        gload16(A  + (size_t)(row0 + m1) * K + k0 + s1 * 8, (char*)As + ch1 * 16);
        gload16(BT + (size_t)(col0 + m0) * K + k0 + s0 * 8, (char*)Bs + ch0 * 16);
        gload16(BT + (size_t)(col0 + m1) * K + k0 + s1 * 8, (char*)Bs + ch1 * 16);
        __syncthreads();

        bh8 aF[4], bF[4];
        #pragma unroll
        for (int mi = 0; mi < 4; ++mi)
            aF[mi] = *(const bh8*)&As[(wr * 64 + mi * 16 + c) * BK + quad * 8];
        #pragma unroll
        for (int ni = 0; ni < 4; ++ni)
            bF[ni] = *(const bh8*)&Bs[(wc * 64 + ni * 16 + c) * BK + quad * 8];
        #pragma unroll
        for (int mi = 0; mi < 4; ++mi)
            #pragma unroll
            for (int ni = 0; ni < 4; ++ni)
                acc[mi][ni] = __builtin_amdgcn_mfma_f32_16x16x32_bf16(
                    aF[mi], bF[ni], acc[mi][ni], 0, 0, 0);
        __syncthreads();
    }

    #pragma unroll
    for (int mi = 0; mi < 4; ++mi)
        #pragma unroll
        for (int ni = 0; ni < 4; ++ni)
            #pragma unroll
            for (int r = 0; r < 4; ++r) {
                int orow = row0 + wr * 64 + mi * 16 + quad * 4 + r;
                int ocol = col0 + wc * 64 + ni * 16 + c;
                if (OUT_BF16)
                    ((short*)C)[(size_t)orow * N + ocol] = f2bf(acc[mi][ni][r]);
                else
                    ((float*)C)[(size_t)orow * N + ocol] = acc[mi][ni][r];
            }
}

// ---------------------------------------------------------------------------
__global__ __launch_bounds__(256)
void conv_bf16(const float* __restrict__ x, short* __restrict__ y)
{
    int idx = (blockIdx.x * 256 + threadIdx.x) * 8;
    bh8 o;
    #pragma unroll
    for (int e = 0; e < 8; ++e) o[e] = f2bf(x[idx + e]);
    *(bh8*)(y + idx) = o;
}

// ---------------------------------------------------------------------------
__global__ __launch_bounds__(256)
void transp_conv(const float* __restrict__ B, short* __restrict__ BT,
                 int K, int N)
{
    __shared__ float tile[64][68];
    const int n0 = blockIdx.x * 64, k0 = blockIdx.y * 64;
    const int t = threadIdx.x;
    const int row = t >> 2, c4 = t & 3;
    const float* src = B + (size_t)(k0 + row) * N + n0 + c4 * 16;
    #pragma unroll
    for (int u = 0; u < 4; ++u) {
        float4 v = *(const float4*)(src + u * 4);
        tile[row][c4 * 16 + u * 4 + 0] = v.x;
        tile[row][c4 * 16 + u * 4 + 1] = v.y;
        tile[row][c4 * 16 + u * 4 + 2] = v.z;
        tile[row][c4 * 16 + u * 4 + 3] = v.w;
    }
    __syncthreads();
    const int nl = t >> 2, kc = t & 3;
    short tmp[16];
    #pragma unroll
    for (int e = 0; e < 16; ++e) tmp[e] = f2bf(tile[kc * 16 + e][nl]);
    short* dst = BT + (size_t)(n0 + nl) * K + k0 + kc * 16;
    *(bh8*)dst = *(bh8*)&tmp[0];
    *(bh8*)(dst + 8) = *(bh8*)&tmp[8];
}

// ---------------------------------------------------------------------------
__global__ __launch_bounds__(256)
void prep_kv(const short* __restrict__ headsb, short* __restrict__ kb,
             short* __restrict__ vT)
{
    __shared__ short vtile[64][72];
    const int bn = blockIdx.x, jt = blockIdx.y;
    const int b = bn & 3, n = bn >> 2;
    const int j0 = jt * 64;
    const int t = threadIdx.x;
    const int row = t >> 2, d0 = (t & 3) * 16;

    const short* kp = headsb + ((size_t)(j0 + row) * 4 + b) * 3072 + 1024 + n * 64 + d0;
    const short* vp = kp + 1024;

    bh8 kv0 = *(const bh8*)kp, kv1 = *(const bh8*)(kp + 8);
    bh8 vv0 = *(const bh8*)vp, vv1 = *(const bh8*)(vp + 8);
    short* kdst = kb + ((size_t)bn * 1024 + j0 + row) * 64 + d0;
    *(bh8*)kdst = kv0;
    *(bh8*)(kdst + 8) = kv1;
    #pragma unroll
    for (int e = 0; e < 8; ++e) {
        vtile[row][d0 + e] = vv0[e];
        vtile[row][d0 + 8 + e] = vv1[e];
    }
    __syncthreads();
    const int d = t >> 2, jl0 = (t & 3) * 16;
    short tmp[16];
    #pragma unroll
    for (int e = 0; e < 16; ++e) tmp[e] = vtile[jl0 + e][d];
    short* vdst = vT + ((size_t)bn * 64 + d) * 1024 + j0 + jl0;
    *(bh8*)vdst = *(bh8*)&tmp[0];
    *(bh8*)(vdst + 8) = *(bh8*)&tmp[8];
}

// ---------------------------------------------------------------------------
// Wave-autonomous MFMA flash attention with fused rel-shift.
// Shear gather is row-dependent: S[row][jj] needs Bt[row][jj + 15 - row]
// (round-6 bug: the -row term was dropped). Single-bpermute form: with
// o = 15 - row (quad-uniform), dest lane c pulls from src lane (c+o)&15 of
// the same quad; the source pre-selects bt[jt+1] when its own c < o (carry
// detection: carry <=> src_c < o). Verified on both carry branches.
// l is a ones-operand PV MFMA column; sP double-buffered -> 1 fence/unit.
// ---------------------------------------------------------------------------
__global__ __launch_bounds__(256)
void attn_mfma(const short* __restrict__ headsb, const short* __restrict__ rkb,
               const short* __restrict__ kb, const short* __restrict__ vT,
               const float* __restrict__ rwb, const float* __restrict__ rrb,
               short* __restrict__ vecb)
{
    __shared__ alignas(16) short sP[4][2][16 * 80];   // [wave][parity]

    const int tid = threadIdx.x;
    const int wave = tid >> 6, lane = tid & 63;
    const int quad = lane >> 4, c = lane & 15;

    // XCD-aware swizzle: same head n lands on one XCD (speed heuristic only)
    const int F = blockIdx.x + 8 * blockIdx.y;   // 0..511
    const int n = (F & 7) + ((F >> 3) >= 32 ? 8 : 0);
    const int rem = (F >> 3) & 31;
    const int b = rem & 3;
    const int pair = rem >> 2;                   // 0..7
    const int sA = 4 * pair + wave;              // sub-tile 0..31
    const int sB = 63 - sA;                      // partner 32..63
    const int nU_A = pair + 1;                   // j-units for strip A
    const int bn = n * 4 + b;

    const int dq = n * 64 + quad * 8;
    const short* kbp = kb + (size_t)bn * 1024 * 64;
    const short* vtp = vT + (size_t)bn * 64 * 1024;

    // ones B-fragment (bf16 1.0 = 0x3F80) for the l-column PV MFMA
    bh8 ones;
    #pragma unroll
    for (int e = 0; e < 8; ++e) ones[e] = (short)0x3F80;

    bh8 aAC[2], aBD[2];
    auto load_q = [&](int rb) {
        #pragma unroll
        for (int ks = 0; ks < 2; ++ks) {
            const short* qp = headsb + ((size_t)(rb + c) * 4 + b) * 3072 + dq + 32 * ks;
            bh8 q8 = *(const bh8*)qp;
            #pragma unroll
            for (int e = 0; e < 8; ++e) {
                float qv = bf2f(q8[e]);
                aAC[ks][e] = f2bf(qv + rwb[dq + 32 * ks + e]);
                aBD[ks][e] = f2bf(qv + rrb[dq + 32 * ks + e]);
            }
        }
    };

    bh8 rkv[10], kbv[8];
    auto pf = [&](int rb, int j0) {
        const int jrw0 = 1008 - rb + j0;
        #pragma unroll
        for (int tt = 0; tt < 5; ++tt) {
            const short* rp = rkb + (size_t)(jrw0 + c + 16 * tt) * 1024 + dq;
            rkv[2 * tt]     = *(const bh8*)rp;
            rkv[2 * tt + 1] = *(const bh8*)(rp + 32);
        }
        #pragma unroll
        for (int jt = 0; jt < 4; ++jt) {
            const short* kp = kbp + (size_t)(j0 + c + 16 * jt) * 64 + quad * 8;
            kbv[2 * jt]     = *(const bh8*)kp;
            kbv[2 * jt + 1] = *(const bh8*)(kp + 32);
        }
    };

    f32x4 oacc[4], lacc;   // lacc = running row-sum column (l)
    float m_r[4];
    #pragma unroll
    for (int dt = 0; dt < 4; ++dt) oacc[dt] = (f32x4)0.0f;
    lacc = (f32x4)0.0f;
    #pragma unroll
    for (int r = 0; r < 4; ++r) m_r[r] = -3.0e38f;

    auto epi = [&](int rb) {
        #pragma unroll
        for (int r = 0; r < 4; ++r) {
            float rinv = 1.f / lacc[r];
            int gi = rb + quad * 4 + r;
            short* op = vecb + ((size_t)gi * 4 + b) * 1024 + n * 64;
            #pragma unroll
            for (int dt = 0; dt < 4; ++dt)
                op[c + 16 * dt] = f2bf(oacc[dt][r] * rinv);
        }
    };

    int rb = sA * 16;
    load_q(rb);
    pf(rb, 0);
    int j0 = 0;

    for (int u = 0; u < 17; ++u) {
        short* PL = &sP[wave][u & 1][0];

        // V fragments for current unit (consumed after softmax - long window)
        bh8 vvv[8];
        #pragma unroll
        for (int dt = 0; dt < 4; ++dt) {
            const short* vp = vtp + (size_t)(c + 16 * dt) * 1024 + j0 + quad * 8;
            vvv[2 * dt]     = *(const bh8*)vp;
            vvv[2 * dt + 1] = *(const bh8*)(vp + 32);
        }

        // ---- phase A: Bt and AC MFMAs from prefetched fragments ----
        f32x4 bt[5];
        #pragma unroll
        for (int tt = 0; tt < 5; ++tt) {
            bt[tt] = (f32x4)0.0f;
            bt[tt] = __builtin_amdgcn_mfma_f32_16x16x32_bf16(aBD[0], rkv[2 * tt], bt[tt], 0, 0, 0);
            bt[tt] = __builtin_amdgcn_mfma_f32_16x16x32_bf16(aBD[1], rkv[2 * tt + 1], bt[tt], 0, 0, 0);
        }
        f32x4 ac[4];
        #pragma unroll
        for (int jt = 0; jt < 4; ++jt) {
            ac[jt] = (f32x4)0.0f;
            ac[jt] = __builtin_amdgcn_mfma_f32_16x16x32_bf16(aAC[0], kbv[2 * jt], ac[jt], 0, 0, 0);
            ac[jt] = __builtin_amdgcn_mfma_f32_16x16x32_bf16(aAC[1], kbv[2 * jt + 1], ac[jt], 0, 0, 0);
        }

        // ---- issue prefetch for next unit (stays in flight across fence) ----
        if (u < 16) {
            int nrb = rb, nj0 = j0 + 64;
            if (u + 1 == nU_A) { nrb = sB * 16; nj0 = 0; }
            pf(nrb, nj0);
        }

        // ---- row-dependent shear gather + mask + online softmax ----
        // Need Bt[row][t], t = c + 16*jt + o, o = 15 - row. Src lane (same
        // quad) c' = (c+o)&15; carry (use bt[jt+1]) <=> c' < o, computed in
        // the SOURCE lane (o is quad-uniform, jt/r are unrolled constants).
        float al[4];
        #pragma unroll
        for (int r = 0; r < 4; ++r) {
            const int row = quad * 4 + r;
            const int o = 15 - row;                         // 0..15
            const int src = (lane & 48) | ((c + o) & 15);
            const int gi = rb + row;
            float s[4];
            float mx = -3.0e38f;
            #pragma unroll
            for (int jt = 0; jt < 4; ++jt) {
                float sval = (c < o) ? bt[jt + 1][r] : bt[jt][r];
                float bd = __shfl(sval, src, 64);
                int gj = j0 + c + 16 * jt;
                float v = SCALE * (ac[jt][r] + bd);
                if (gj > gi) v = NEGF;
                s[jt] = v;
                mx = fmaxf(mx, v);
            }
            #pragma unroll
            for (int msk = 1; msk < 16; msk <<= 1)
                mx = fmaxf(mx, __shfl_xor(mx, msk, 64));
            float mnew = fmaxf(m_r[r], mx);
            al[r] = __expf(m_r[r] - mnew);
            m_r[r] = mnew;
            #pragma unroll
            for (int jt = 0; jt < 4; ++jt)
                PL[row * 80 + c + 16 * jt] = f2bf(__expf(s[jt] - mnew));
            #pragma unroll
            for (int dt = 0; dt < 4; ++dt) oacc[dt][r] *= al[r];
            lacc[r] *= al[r];
        }

        wave_lds_fence();   // P writes -> aP reads (same wave; only fence/unit)

        // ---- PV: O += P @ V, l += P @ 1 ----
        bh8 aP[2];
        #pragma unroll
        for (int ks = 0; ks < 2; ++ks)
            aP[ks] = *(const bh8*)(PL + c * 80 + 32 * ks + quad * 8);
        #pragma unroll
        for (int dt = 0; dt < 4; ++dt) {
            oacc[dt] = __builtin_amdgcn_mfma_f32_16x16x32_bf16(aP[0], vvv[2 * dt], oacc[dt], 0, 0, 0);
            oacc[dt] = __builtin_amdgcn_mfma_f32_16x16x32_bf16(aP[1], vvv[2 * dt + 1], oacc[dt], 0, 0, 0);
        }
        lacc = __builtin_amdgcn_mfma_f32_16x16x32_bf16(aP[0], ones, lacc, 0, 0, 0);
        lacc = __builtin_amdgcn_mfma_f32_16x16x32_bf16(aP[1], ones, lacc, 0, 0, 0);

        // ---- strip switch ----
        if (u + 1 == nU_A) {
            epi(rb);
            #pragma unroll
            for (int dt = 0; dt < 4; ++dt) oacc[dt] = (f32x4)0.0f;
            lacc = (f32x4)0.0f;
            #pragma unroll
            for (int r = 0; r < 4; ++r) m_r[r] = -3.0e38f;
            rb = sB * 16;
            load_q(rb);
            j0 = 0;
        } else {
            j0 += 64;
        }
    }
    epi(rb);
}

// ---------------------------------------------------------------------------
__global__ __launch_bounds__(256)
void ln_kernel(const float* __restrict__ w, const float* __restrict__ attn,
               const float* __restrict__ gamma, const float* __restrict__ beta,
               float* __restrict__ out)
{
    const int row = blockIdx.x;
    const int tid = threadIdx.x;
    const float* xw = w + row * DMODEL;
    const float* xa = attn + row * DMODEL;

    float x[4];
    float s = 0.f;
    #pragma unroll
    for (int e = 0; e < 4; ++e) {
        int cc = tid + e * 256;
        x[e] = xw[cc] + xa[cc];
        s += x[e];
    }
    __shared__ float red[6];
    #pragma unroll
    for (int m = 1; m < 64; m <<= 1) s += __shfl_xor(s, m, 64);
    int wv = tid >> 6, lnid = tid & 63;
    if (lnid == 0) red[wv] = s;
    __syncthreads();
    if (tid == 0) red[4] = red[0] + red[1] + red[2] + red[3];
    __syncthreads();
    float mu = red[4] * (1.f / DMODEL);

    float vs = 0.f;
    #pragma unroll
    for (int e = 0; e < 4; ++e) { float d = x[e] - mu; vs += d * d; }
    #pragma unroll
    for (int m = 1; m < 64; m <<= 1) vs += __shfl_xor(vs, m, 64);
    if (lnid == 0) red[wv] = vs;
    __syncthreads();
    if (tid == 0) red[5] = red[0] + red[1] + red[2] + red[3];
    __syncthreads();
    float var = red[5] * (1.f / DMODEL);
    float inv = rsqrtf(var + 1e-5f);

    #pragma unroll
    for (int e = 0; e < 4; ++e) {
        int cc = tid + e * 256;
        out[row * DMODEL + cc] = (x[e] - mu) * inv * gamma[cc] + beta[cc];
    }
}

// ---------------------------------------------------------------------------
extern "C" void kernel_launch(void* const* d_in, const int* in_sizes, int n_in,
                              void* d_out, int out_size, void* d_ws, size_t ws_size,
                              hipStream_t stream)
{
    const float* w     = (const float*)d_in[0];
    const float* r     = (const float*)d_in[1];
    const float* rwb   = (const float*)d_in[2];
    const float* rrb   = (const float*)d_in[3];
    // d_in[4] = attn_mask: deterministically causal-tril, applied analytically.
    const float* Wqkv  = (const float*)d_in[5];
    const float* Wr    = (const float*)d_in[6];
    const float* Wo    = (const float*)d_in[7];
    const float* gamma = (const float*)d_in[8];
    const float* beta  = (const float*)d_in[9];
    float* out = (float*)d_out;

    short* headsb = (short*)d_ws;                 // 12,582,912  [4096][3072] bf16
    short* wb     = headsb + 12582912;            //  4,194,304  [4096][1024]
    short* WqkvT  = wb + 4194304;                 //  3,145,728  [3072][1024]
    short* rb     = WqkvT + 3145728;              //  1,048,576  [1024][1024]
    short* WrT    = rb + 1048576;                 //  1,048,576
    short* WoT    = WrT + 1048576;                //  1,048,576
    short* rkb    = WoT + 1048576;                //  1,114,112  [1088][1024]
    short* kb     = rkb + 1114112;                //  4,194,304  [bn][j][64]
    short* vTb    = kb + 4194304;                 //  4,194,304  [bn][64][j]
    short* vecb   = vTb + 4194304;                //  4,194,304  [4096][1024]
    float* attno  = (float*)headsb;               //  overlay: headsb dead after attn

    conv_bf16<<<2048, 256, 0, stream>>>(w, wb);
    conv_bf16<<<512, 256, 0, stream>>>(r, rb);
    transp_conv<<<dim3(48, 16), 256, 0, stream>>>(Wqkv, WqkvT, 1024, 3072);
    transp_conv<<<dim3(16, 16), 256, 0, stream>>>(Wr, WrT, 1024, 1024);
    transp_conv<<<dim3(16, 16), 256, 0, stream>>>(Wo, WoT, 1024, 1024);
    gemm_bf16<true><<<dim3(24, 32), 256, 0, stream>>>(wb, WqkvT, headsb, 4096, 3072, 1024);
    gemm_bf16<true><<<dim3(8, 8), 256, 0, stream>>>(rb, WrT, rkb, 1024, 1024, 1024);
    hipMemsetAsync(rkb + 1024 * 1024, 0, 64 * 1024 * sizeof(short), stream);
    prep_kv<<<dim3(64, 16), 256, 0, stream>>>(headsb, kb, vTb);
    attn_mfma<<<dim3(8, 64), 256, 0, stream>>>(headsb, rkb, kb, vTb, rwb, rrb, vecb);
    gemm_bf16<false><<<dim3(8, 32), 256, 0, stream>>>(vecb, WoT, attno, 4096, 1024, 1024);
    ln_kernel<<<4096, 256, 0, stream>>>(w, attno, gamma, beta, out);
}